// Round 6
// baseline (542.083 us; speedup 1.0000x reference)
//
#include <hip/hip_runtime.h>
#include <hip/hip_cooperative_groups.h>

namespace cg = cooperative_groups;

// LiteralE: out[b] = f(index[b]); f(n) = Z*H + (1-Z)*e[n],
// Z = sigmoid(W_ze[n]·e[n] + W_zl[n]·l[n] + b), H = tanh(W_he[n]·e[n] + W_hl[n]·l[n]).
//
// out depends only on n -> compute f once per unique entity, then gather.
// Round 6: single persistent cooperative kernel (zero -> mark -> compute ->
// gather with grid.sync between phases) to remove inter-dispatch drain/ramp
// and aux-kernel launch overhead. Traffic floor unchanged (~1.08 GB).

constexpr int H_DIM = 128;
constexpr int N_D   = 64;
constexpr int N_ENT = 10000;

__global__ __launch_bounds__(256, 4) void k_fused_coop(
    const float* __restrict__ e,
    const float* __restrict__ l,
    const float* __restrict__ W_ze,
    const float* __restrict__ W_zl,
    const float* __restrict__ W_he,
    const float* __restrict__ W_hl,
    const float* __restrict__ bias,
    const int*  __restrict__ index,
    float* __restrict__ out,
    int* used, int* count, int* list,
    float* __restrict__ uout, int B)
{
    cg::grid_group grid = cg::this_grid();

    const int tid      = threadIdx.x;
    const int gtid     = blockIdx.x * blockDim.x + tid;
    const int nthreads = gridDim.x * blockDim.x;

    // ---- Phase 0: zero used[] and count (count sits right after used) ----
    for (int i = gtid; i < N_ENT + 1; i += nthreads) used[i] = 0;
    grid.sync();

    // ---- Phase 1: mark first occurrences into a dense worklist ----
    for (int b = gtid; b < B; b += nthreads) {
        const int n = index[b];
        if (atomicExch(&used[n], 1) == 0) {
            const int p = atomicAdd(count, 1);
            atomicExch(&list[p], n);      // device-scope visible store
        }
    }
    grid.sync();

    // ---- Phase 2: compute f(n) for each unique entity (persistent blocks) ----
    {
        __shared__ float az_s[H_DIM];
        __shared__ float ah_s[H_DIM];

        const int cnt  = *count;          // coherent after grid.sync
        const int wave = tid >> 6;
        const int lane = tid & 63;
        const int g    = lane >> 4;       // row within wave's 4-row group
        const int j    = lane & 15;       // column-chunk lane

        for (int ei = blockIdx.x; ei < cnt; ei += gridDim.x) {
            const long long n = (long long)list[ei];   // uniform broadcast load

            const float4* ep = reinterpret_cast<const float4*>(e + n * H_DIM);
            const float4 xe0 = ep[j];
            const float4 xe1 = ep[j + 16];
            const float4 xl  = reinterpret_cast<const float4*>(l + n * N_D)[j];

            const float4* wze = reinterpret_cast<const float4*>(W_ze + n * (size_t)(H_DIM * H_DIM));
            const float4* whe = reinterpret_cast<const float4*>(W_he + n * (size_t)(H_DIM * H_DIM));
            const float4* wzl = reinterpret_cast<const float4*>(W_zl + n * (size_t)(H_DIM * N_D));
            const float4* whl = reinterpret_cast<const float4*>(W_hl + n * (size_t)(H_DIM * N_D));

            #pragma unroll 4
            for (int pass = 0; pass < 8; ++pass) {
                const int r = pass * 16 + wave * 4 + g;   // row 0..127

                const float4 a0 = wze[r * 32 + j];
                const float4 a1 = wze[r * 32 + j + 16];
                const float4 b0 = whe[r * 32 + j];
                const float4 b1 = whe[r * 32 + j + 16];
                const float4 c0 = wzl[r * 16 + j];
                const float4 d0 = whl[r * 16 + j];

                float pz = fmaf(a0.x, xe0.x, fmaf(a0.y, xe0.y, fmaf(a0.z, xe0.z, a0.w * xe0.w)));
                pz = fmaf(a1.x, xe1.x, fmaf(a1.y, xe1.y, fmaf(a1.z, xe1.z, fmaf(a1.w, xe1.w, pz))));
                pz = fmaf(c0.x, xl.x,  fmaf(c0.y, xl.y,  fmaf(c0.z, xl.z,  fmaf(c0.w, xl.w,  pz))));

                float ph = fmaf(b0.x, xe0.x, fmaf(b0.y, xe0.y, fmaf(b0.z, xe0.z, b0.w * xe0.w)));
                ph = fmaf(b1.x, xe1.x, fmaf(b1.y, xe1.y, fmaf(b1.z, xe1.z, fmaf(b1.w, xe1.w, ph))));
                ph = fmaf(d0.x, xl.x,  fmaf(d0.y, xl.y,  fmaf(d0.z, xl.z,  fmaf(d0.w, xl.w,  ph))));

                #pragma unroll
                for (int m = 1; m <= 8; m <<= 1) {
                    pz += __shfl_xor(pz, m, 64);
                    ph += __shfl_xor(ph, m, 64);
                }
                if (j == 0) { az_s[r] = pz; ah_s[r] = ph; }
            }
            __syncthreads();

            if (tid < H_DIM) {
                const float zg = 1.0f / (1.0f + __expf(-(az_s[tid] + bias[tid])));
                const float hc = tanhf(ah_s[tid]);
                const float ev = e[n * H_DIM + tid];
                uout[n * H_DIM + tid] = zg * hc + (1.0f - zg) * ev;
            }
            __syncthreads();   // protect az_s/ah_s before next entity
        }
    }
    grid.sync();

    // ---- Phase 3: gather out[b] = uout[index[b]] (one float4 per thread) ----
    for (int i = gtid; i < B * (H_DIM / 4); i += nthreads) {
        const int b = i >> 5;
        const int c = i & 31;
        const long long n = (long long)index[b];
        reinterpret_cast<float4*>(out)[(size_t)b * 32 + c] =
            reinterpret_cast<const float4*>(uout)[n * 32 + c];
    }
}

// ---------------- Fallback path (round-4 proven 4-kernel pipeline) ----------------

__global__ void k_mark(const int* __restrict__ index, int* __restrict__ used,
                       int* __restrict__ count, int* __restrict__ list, int B) {
    const int b = blockIdx.x * blockDim.x + threadIdx.x;
    if (b < B) {
        const int n = index[b];
        if (atomicExch(&used[n], 1) == 0) {
            const int p = atomicAdd(count, 1);
            list[p] = n;
        }
    }
}

__global__ __launch_bounds__(256) void k_compute_unique(
    const float* __restrict__ e, const float* __restrict__ l,
    const float* __restrict__ W_ze, const float* __restrict__ W_zl,
    const float* __restrict__ W_he, const float* __restrict__ W_hl,
    const float* __restrict__ bias,
    const int* __restrict__ count, const int* __restrict__ list,
    float* __restrict__ uout)
{
    const int ei = blockIdx.x;
    if (ei >= *count) return;
    const long long n = (long long)list[ei];

    const int tid  = threadIdx.x;
    const int wave = tid >> 6;
    const int lane = tid & 63;
    const int g    = lane >> 4;
    const int j    = lane & 15;

    __shared__ float az_s[H_DIM];
    __shared__ float ah_s[H_DIM];

    const float4* ep = reinterpret_cast<const float4*>(e + n * H_DIM);
    const float4 xe0 = ep[j];
    const float4 xe1 = ep[j + 16];
    const float4 xl  = reinterpret_cast<const float4*>(l + n * N_D)[j];

    const float4* wze = reinterpret_cast<const float4*>(W_ze + n * (size_t)(H_DIM * H_DIM));
    const float4* whe = reinterpret_cast<const float4*>(W_he + n * (size_t)(H_DIM * H_DIM));
    const float4* wzl = reinterpret_cast<const float4*>(W_zl + n * (size_t)(H_DIM * N_D));
    const float4* whl = reinterpret_cast<const float4*>(W_hl + n * (size_t)(H_DIM * N_D));

    #pragma unroll 4
    for (int pass = 0; pass < 8; ++pass) {
        const int r = pass * 16 + wave * 4 + g;
        const float4 a0 = wze[r * 32 + j];
        const float4 a1 = wze[r * 32 + j + 16];
        const float4 b0 = whe[r * 32 + j];
        const float4 b1 = whe[r * 32 + j + 16];
        const float4 c0 = wzl[r * 16 + j];
        const float4 d0 = whl[r * 16 + j];
        float pz = fmaf(a0.x, xe0.x, fmaf(a0.y, xe0.y, fmaf(a0.z, xe0.z, a0.w * xe0.w)));
        pz = fmaf(a1.x, xe1.x, fmaf(a1.y, xe1.y, fmaf(a1.z, xe1.z, fmaf(a1.w, xe1.w, pz))));
        pz = fmaf(c0.x, xl.x,  fmaf(c0.y, xl.y,  fmaf(c0.z, xl.z,  fmaf(c0.w, xl.w,  pz))));
        float ph = fmaf(b0.x, xe0.x, fmaf(b0.y, xe0.y, fmaf(b0.z, xe0.z, b0.w * xe0.w)));
        ph = fmaf(b1.x, xe1.x, fmaf(b1.y, xe1.y, fmaf(b1.z, xe1.z, fmaf(b1.w, xe1.w, ph))));
        ph = fmaf(d0.x, xl.x,  fmaf(d0.y, xl.y,  fmaf(d0.z, xl.z,  fmaf(d0.w, xl.w,  ph))));
        #pragma unroll
        for (int m = 1; m <= 8; m <<= 1) {
            pz += __shfl_xor(pz, m, 64);
            ph += __shfl_xor(ph, m, 64);
        }
        if (j == 0) { az_s[r] = pz; ah_s[r] = ph; }
    }
    __syncthreads();

    if (tid < H_DIM) {
        const float zg = 1.0f / (1.0f + __expf(-(az_s[tid] + bias[tid])));
        const float hc = tanhf(ah_s[tid]);
        const float ev = e[n * H_DIM + tid];
        uout[n * H_DIM + tid] = zg * hc + (1.0f - zg) * ev;
    }
}

__global__ void k_gather(const int* __restrict__ index,
                         const float* __restrict__ uout,
                         float* __restrict__ out, int B)
{
    const int i = blockIdx.x * blockDim.x + threadIdx.x;
    if (i < B * (H_DIM / 4)) {
        const int b = i >> 5;
        const int c = i & 31;
        const long long n = (long long)index[b];
        reinterpret_cast<float4*>(out)[(size_t)b * 32 + c] =
            reinterpret_cast<const float4*>(uout)[n * 32 + c];
    }
}

extern "C" void kernel_launch(void* const* d_in, const int* in_sizes, int n_in,
                              void* d_out, int out_size, void* d_ws, size_t ws_size,
                              hipStream_t stream) {
    const float* e    = (const float*)d_in[0];
    const float* l    = (const float*)d_in[1];
    const float* W_ze = (const float*)d_in[2];
    const float* W_zl = (const float*)d_in[3];
    const float* W_he = (const float*)d_in[4];
    const float* W_hl = (const float*)d_in[5];
    const float* bias = (const float*)d_in[6];
    const int*   idx  = (const int*)d_in[7];
    float* out = (float*)d_out;

    const int B = in_sizes[7];   // 8192

    const size_t uout_bytes = (size_t)N_ENT * H_DIM * sizeof(float);   // 5.12 MB
    const size_t need = uout_bytes + (size_t)(2 * N_ENT + 1) * sizeof(int);

    if (ws_size < need) return;   // (harness always provides enough)

    float* uout  = (float*)d_ws;
    int*   used  = (int*)((char*)d_ws + uout_bytes);   // [N_ENT]
    int*   count = used + N_ENT;                        // [1] (zeroed with used)
    int*   list  = count + 1;                           // [N_ENT]

    // --- Try the fused persistent cooperative kernel first ---
    int B_arg = B;
    void* args[] = {
        (void*)&e, (void*)&l, (void*)&W_ze, (void*)&W_zl, (void*)&W_he,
        (void*)&W_hl, (void*)&bias, (void*)&idx, (void*)&out,
        (void*)&used, (void*)&count, (void*)&list, (void*)&uout, (void*)&B_arg
    };
    hipError_t err = hipLaunchCooperativeKernel(
        (const void*)k_fused_coop, dim3(1024), dim3(256), args, 0, stream);

    if (err != hipSuccess) {
        // --- Fallback: proven 4-dispatch pipeline ---
        hipMemsetAsync(used, 0, (size_t)(N_ENT + 1) * sizeof(int), stream);
        k_mark<<<dim3((B + 255) / 256), dim3(256), 0, stream>>>(idx, used, count, list, B);
        k_compute_unique<<<dim3(N_ENT), dim3(256), 0, stream>>>(
            e, l, W_ze, W_zl, W_he, W_hl, bias, count, list, uout);
        k_gather<<<dim3((B * (H_DIM / 4) + 255) / 256), dim3(256), 0, stream>>>(
            idx, uout, out, B);
    }
}

// Round 8
// 181.399 us; speedup vs baseline: 2.9883x; 2.9883x over previous
//
#include <hip/hip_runtime.h>

// LiteralE: out[b] = f(index[b]); f(n) = Z*H + (1-Z)*e[n],
// Z = sigmoid(W_ze[n]·e[n] + W_zl[n]·l[n] + b), H = tanh(W_he[n]·e[n] + W_hl[n]·l[n]).
//
// out depends only on n -> compute f once per unique entity, then gather.
// Round 8: round-7 retry with native ext_vector_type for nontemporal loads
// (__builtin_nontemporal_load rejects HIP_vector_type pointers).

constexpr int H_DIM = 128;
constexpr int N_D   = 64;
constexpr int N_ENT = 10000;

typedef float f4 __attribute__((ext_vector_type(4)));   // layout == float4

// Mark: used[n] <- 1 for every entity in the batch. Works under any prior ws
// content; compute resets to 0 afterwards (deterministic across calls).
// Spurious preexisting 1s only cause extra compute whose output is unread.
__global__ void k_mark(const int* __restrict__ index, int* __restrict__ used, int B) {
    const int b = blockIdx.x * blockDim.x + threadIdx.x;
    if (b < B) atomicExch(&used[index[b]], 1);
}

// One block per entity id (XCD-chunk swizzled); early-out if not marked.
__global__ __launch_bounds__(256) void k_compute_unique(
    const float* __restrict__ e,
    const float* __restrict__ l,
    const float* __restrict__ W_ze,
    const float* __restrict__ W_zl,
    const float* __restrict__ W_he,
    const float* __restrict__ W_hl,
    const float* __restrict__ bias,
    int* __restrict__ used,
    float* __restrict__ uout)
{
    // 10000 % 8 == 0: XCD k streams entities [k*1250, (k+1)*1250).
    const int bid = blockIdx.x;
    const long long n = (long long)((bid & 7) * (N_ENT / 8) + (bid >> 3));
    if (used[n] != 1) return;

    const int tid  = threadIdx.x;
    const int wave = tid >> 6;
    const int lane = tid & 63;
    const int g    = lane >> 4;        // row within wave's 4-row group
    const int j    = lane & 15;        // column-chunk lane

    __shared__ float az_s[H_DIM];
    __shared__ float ah_s[H_DIM];

    const f4* ep = reinterpret_cast<const f4*>(e + n * H_DIM);
    const f4 xe0 = ep[j];
    const f4 xe1 = ep[j + 16];
    const f4 xl  = reinterpret_cast<const f4*>(l + n * N_D)[j];

    const f4* wze = reinterpret_cast<const f4*>(W_ze + n * (size_t)(H_DIM * H_DIM));
    const f4* whe = reinterpret_cast<const f4*>(W_he + n * (size_t)(H_DIM * H_DIM));
    const f4* wzl = reinterpret_cast<const f4*>(W_zl + n * (size_t)(H_DIM * N_D));
    const f4* whl = reinterpret_cast<const f4*>(W_hl + n * (size_t)(H_DIM * N_D));

    #pragma unroll 4
    for (int pass = 0; pass < 8; ++pass) {
        const int r = pass * 16 + wave * 4 + g;   // row 0..127

        // Weights are read exactly once -> non-temporal (skip cache retention).
        const f4 a0 = __builtin_nontemporal_load(&wze[r * 32 + j]);
        const f4 a1 = __builtin_nontemporal_load(&wze[r * 32 + j + 16]);
        const f4 b0 = __builtin_nontemporal_load(&whe[r * 32 + j]);
        const f4 b1 = __builtin_nontemporal_load(&whe[r * 32 + j + 16]);
        const f4 c0 = __builtin_nontemporal_load(&wzl[r * 16 + j]);
        const f4 d0 = __builtin_nontemporal_load(&whl[r * 16 + j]);

        float pz = fmaf(a0.x, xe0.x, fmaf(a0.y, xe0.y, fmaf(a0.z, xe0.z, a0.w * xe0.w)));
        pz = fmaf(a1.x, xe1.x, fmaf(a1.y, xe1.y, fmaf(a1.z, xe1.z, fmaf(a1.w, xe1.w, pz))));
        pz = fmaf(c0.x, xl.x,  fmaf(c0.y, xl.y,  fmaf(c0.z, xl.z,  fmaf(c0.w, xl.w,  pz))));

        float ph = fmaf(b0.x, xe0.x, fmaf(b0.y, xe0.y, fmaf(b0.z, xe0.z, b0.w * xe0.w)));
        ph = fmaf(b1.x, xe1.x, fmaf(b1.y, xe1.y, fmaf(b1.z, xe1.z, fmaf(b1.w, xe1.w, ph))));
        ph = fmaf(d0.x, xl.x,  fmaf(d0.y, xl.y,  fmaf(d0.z, xl.z,  fmaf(d0.w, xl.w,  ph))));

        #pragma unroll
        for (int m = 1; m <= 8; m <<= 1) {
            pz += __shfl_xor(pz, m, 64);
            ph += __shfl_xor(ph, m, 64);
        }
        if (j == 0) { az_s[r] = pz; ah_s[r] = ph; }
    }
    __syncthreads();

    if (tid < H_DIM) {
        const float zg = 1.0f / (1.0f + __expf(-(az_s[tid] + bias[tid])));
        const float hc = tanhf(ah_s[tid]);
        const float ev = e[n * H_DIM + tid];
        uout[n * H_DIM + tid] = zg * hc + (1.0f - zg) * ev;
    }
    if (tid == 0) used[n] = 0;   // restore ws state for the next call
}

__global__ void k_gather(const int* __restrict__ index,
                         const float* __restrict__ uout,
                         float* __restrict__ out, int B)
{
    const int i = blockIdx.x * blockDim.x + threadIdx.x;   // one float4 each
    if (i < B * (H_DIM / 4)) {
        const int b = i >> 5;
        const int c = i & 31;
        const long long n = (long long)index[b];
        reinterpret_cast<float4*>(out)[(size_t)b * 32 + c] =
            reinterpret_cast<const float4*>(uout)[n * 32 + c];
    }
}

// ---- Fallback (monolithic, round-2 proven) if ws is ever too small ----
__global__ __launch_bounds__(256) void literal_e_fused(
    const float* __restrict__ e, const float* __restrict__ l,
    const float* __restrict__ W_ze, const float* __restrict__ W_zl,
    const float* __restrict__ W_he, const float* __restrict__ W_hl,
    const float* __restrict__ bias, const int* __restrict__ index,
    float* __restrict__ out)
{
    const int tid  = threadIdx.x;
    const int wave = tid >> 6;
    const int lane = tid & 63;
    const int g    = lane >> 4;
    const int j    = lane & 15;

    __shared__ float az_s[H_DIM];
    __shared__ float ah_s[H_DIM];

    const long long bi = blockIdx.x;
    const long long n  = (long long)index[bi];

    const float4* ep = reinterpret_cast<const float4*>(e + n * H_DIM);
    const float4 xe0 = ep[j];
    const float4 xe1 = ep[j + 16];
    const float4 xl  = reinterpret_cast<const float4*>(l + n * N_D)[j];

    const float4* wze = reinterpret_cast<const float4*>(W_ze + n * (size_t)(H_DIM * H_DIM));
    const float4* whe = reinterpret_cast<const float4*>(W_he + n * (size_t)(H_DIM * H_DIM));
    const float4* wzl = reinterpret_cast<const float4*>(W_zl + n * (size_t)(H_DIM * N_D));
    const float4* whl = reinterpret_cast<const float4*>(W_hl + n * (size_t)(H_DIM * N_D));

    #pragma unroll 4
    for (int pass = 0; pass < 8; ++pass) {
        const int r = pass * 16 + wave * 4 + g;
        const float4 a0 = wze[r * 32 + j];
        const float4 a1 = wze[r * 32 + j + 16];
        const float4 b0 = whe[r * 32 + j];
        const float4 b1 = whe[r * 32 + j + 16];
        const float4 c0 = wzl[r * 16 + j];
        const float4 d0 = whl[r * 16 + j];
        float pz = fmaf(a0.x, xe0.x, fmaf(a0.y, xe0.y, fmaf(a0.z, xe0.z, a0.w * xe0.w)));
        pz = fmaf(a1.x, xe1.x, fmaf(a1.y, xe1.y, fmaf(a1.z, xe1.z, fmaf(a1.w, xe1.w, pz))));
        pz = fmaf(c0.x, xl.x,  fmaf(c0.y, xl.y,  fmaf(c0.z, xl.z,  fmaf(c0.w, xl.w,  pz))));
        float ph = fmaf(b0.x, xe0.x, fmaf(b0.y, xe0.y, fmaf(b0.z, xe0.z, b0.w * xe0.w)));
        ph = fmaf(b1.x, xe1.x, fmaf(b1.y, xe1.y, fmaf(b1.z, xe1.z, fmaf(b1.w, xe1.w, ph))));
        ph = fmaf(d0.x, xl.x,  fmaf(d0.y, xl.y,  fmaf(d0.z, xl.z,  fmaf(d0.w, xl.w,  ph))));
        #pragma unroll
        for (int m = 1; m <= 8; m <<= 1) {
            pz += __shfl_xor(pz, m, 64);
            ph += __shfl_xor(ph, m, 64);
        }
        if (j == 0) { az_s[r] = pz; ah_s[r] = ph; }
    }
    __syncthreads();

    if (tid < H_DIM) {
        const float zg = 1.0f / (1.0f + __expf(-(az_s[tid] + bias[tid])));
        const float hc = tanhf(ah_s[tid]);
        const float ev = e[n * H_DIM + tid];
        out[bi * H_DIM + tid] = zg * hc + (1.0f - zg) * ev;
    }
}

extern "C" void kernel_launch(void* const* d_in, const int* in_sizes, int n_in,
                              void* d_out, int out_size, void* d_ws, size_t ws_size,
                              hipStream_t stream) {
    const float* e    = (const float*)d_in[0];
    const float* l    = (const float*)d_in[1];
    const float* W_ze = (const float*)d_in[2];
    const float* W_zl = (const float*)d_in[3];
    const float* W_he = (const float*)d_in[4];
    const float* W_hl = (const float*)d_in[5];
    const float* bias = (const float*)d_in[6];
    const int*   idx  = (const int*)d_in[7];
    float* out = (float*)d_out;

    const int B = in_sizes[7];   // 8192

    const size_t uout_bytes = (size_t)N_ENT * H_DIM * sizeof(float);   // 5.12 MB
    const size_t need = uout_bytes + (size_t)N_ENT * sizeof(int);

    if (ws_size >= need) {
        float* uout = (float*)d_ws;
        int*   used = (int*)((char*)d_ws + uout_bytes);   // [N_ENT]

        k_mark<<<dim3((B + 255) / 256), dim3(256), 0, stream>>>(idx, used, B);
        k_compute_unique<<<dim3(N_ENT), dim3(256), 0, stream>>>(
            e, l, W_ze, W_zl, W_he, W_hl, bias, used, uout);
        k_gather<<<dim3((B * (H_DIM / 4) + 255) / 256), dim3(256), 0, stream>>>(
            idx, uout, out, B);
    } else {
        literal_e_fused<<<dim3(B), dim3(256), 0, stream>>>(
            e, l, W_ze, W_zl, W_he, W_hl, bias, idx, out);
    }
}